// Round 1
// baseline (187.782 us; speedup 1.0000x reference)
//
#include <hip/hip_runtime.h>

#define MDIM 2048   // B
#define KDIM 2560   // HEAD
#define NHID 2048   // N_HID
#define INF 512

#define BM 128
#define BN 128
#define BK 64

typedef __attribute__((ext_vector_type(4))) float f32x4;
typedef __attribute__((ext_vector_type(8))) short short8;
typedef __attribute__((ext_vector_type(8))) unsigned short ushort8v;
typedef __attribute__((ext_vector_type(4))) unsigned short ushort4v;

__device__ __forceinline__ unsigned short f2bf(float f) {
    unsigned u = __float_as_uint(f);
    u += 0x7fffu + ((u >> 16) & 1u);   // round-to-nearest-even
    return (unsigned short)(u >> 16);
}
__device__ __forceinline__ float bf2f(unsigned short s) {
    return __uint_as_float(((unsigned)s) << 16);
}

// ---------------- prep: xc = concat(x, hidden) -> bf16 [MDIM][KDIM] ----------------
__global__ void prep_xc(const float* __restrict__ x, const float* __restrict__ h,
                        unsigned short* __restrict__ xc) {
    int idx = blockIdx.x * 256 + threadIdx.x;   // 8 elems / thread
    int e = idx * 8;
    int b = e / KDIM;
    int c = e - b * KDIM;
    const float* src = (c < INF) ? (x + (size_t)b * INF + c)
                                 : (h + (size_t)b * NHID + (c - INF));
    float4 v0 = *(const float4*)src;
    float4 v1 = *(const float4*)(src + 4);
    ushort8v o;
    o[0] = f2bf(v0.x); o[1] = f2bf(v0.y); o[2] = f2bf(v0.z); o[3] = f2bf(v0.w);
    o[4] = f2bf(v1.x); o[5] = f2bf(v1.y); o[6] = f2bf(v1.z); o[7] = f2bf(v1.w);
    *(ushort8v*)(xc + e) = o;
}

// ---------------- prep: Wm[k] = W_k * mask -> bf16, 5 planes [NHID][KDIM] ----------------
__global__ void prep_wm(const float* __restrict__ Wg, const float* __restrict__ Wh,
                        const float* __restrict__ Wfg, const float* __restrict__ Wfh,
                        const float* __restrict__ Wp, const float* __restrict__ mask,
                        unsigned short* __restrict__ Wm) {
    int idx = blockIdx.x * 256 + threadIdx.x;   // 4 elems / thread, all 5 planes
    size_t e = (size_t)idx * 4;
    const size_t PL = (size_t)NHID * KDIM;
    float4 m = *(const float4*)(mask + e);
    const float* Ws[5] = {Wg, Wh, Wfg, Wfh, Wp};
    #pragma unroll
    for (int k = 0; k < 5; ++k) {
        float4 w = *(const float4*)(Ws[k] + e);
        ushort4v o;
        o[0] = f2bf(w.x * m.x); o[1] = f2bf(w.y * m.y);
        o[2] = f2bf(w.z * m.z); o[3] = f2bf(w.w * m.w);
        *(ushort4v*)(Wm + k * PL + e) = o;
    }
}

// ---------------- GEMM: C = A (MxK) . B^T (NxK), bf16 in, bf16 out ----------------
// A = xc [MDIM][KDIM], B = Wm [5*NHID][KDIM], C = [5][MDIM][NHID]
__global__ __launch_bounds__(256, 2) void gemm_bt(
    const unsigned short* __restrict__ A,
    const unsigned short* __restrict__ B,
    unsigned short* __restrict__ C) {
    __shared__ unsigned short lsA[BM * BK];   // 16 KB
    __shared__ unsigned short lsB[BN * BK];   // 16 KB

    const int tid  = threadIdx.x;
    const int m0   = blockIdx.y * BM;
    const int n0   = blockIdx.x * BN;
    const int lane = tid & 63;
    const int wave = tid >> 6;
    const int wr   = (wave >> 1) * 64;   // wave row offset in tile
    const int wc   = (wave & 1) * 64;    // wave col offset in tile
    const int lr   = lane & 15;
    const int kq   = lane >> 4;          // 0..3

    f32x4 acc[4][4] = {};

    // staging geometry: 256 threads x 16B covers 32 rows x 64 cols per round, 4 rounds
    const int arow = tid >> 3;           // 0..31
    const int acol = (tid & 7) * 8;      // 0,8,..,56
    const unsigned short* gA = A + (size_t)(m0 + arow) * KDIM + acol;
    const unsigned short* gB = B + (size_t)(n0 + arow) * KDIM + acol;
    unsigned short* lA = lsA + tid * 8;
    unsigned short* lB = lsB + tid * 8;

    for (int kt = 0; kt < KDIM / BK; ++kt) {
        __syncthreads();   // previous compute done before overwrite
        #pragma unroll
        for (int i = 0; i < 4; ++i) {
            __builtin_amdgcn_global_load_lds(
                (const __attribute__((address_space(1))) unsigned int*)(gA + (size_t)i * 32 * KDIM),
                (__attribute__((address_space(3))) unsigned int*)(lA + i * 32 * BK),
                16, 0, 0);
            __builtin_amdgcn_global_load_lds(
                (const __attribute__((address_space(1))) unsigned int*)(gB + (size_t)i * 32 * KDIM),
                (__attribute__((address_space(3))) unsigned int*)(lB + i * 32 * BK),
                16, 0, 0);
        }
        gA += BK; gB += BK;
        __syncthreads();   // staging complete (compiler drains vmcnt before barrier)

        #pragma unroll
        for (int kk = 0; kk < BK / 32; ++kk) {
            short8 af[4], bfr[4];
            #pragma unroll
            for (int m = 0; m < 4; ++m)
                af[m] = *(const short8*)(lsA + (wr + m * 16 + lr) * BK + kk * 32 + kq * 8);
            #pragma unroll
            for (int n = 0; n < 4; ++n)
                bfr[n] = *(const short8*)(lsB + (wc + n * 16 + lr) * BK + kk * 32 + kq * 8);
            #pragma unroll
            for (int m = 0; m < 4; ++m) {
                #pragma unroll
                for (int n = 0; n < 4; ++n) {
                    acc[m][n] = __builtin_amdgcn_mfma_f32_16x16x32_bf16(
                        af[m], bfr[n], acc[m][n], 0, 0, 0);
                }
            }
        }
    }

    // C/D layout: col = lane&15, row = (lane>>4)*4 + reg
    const int kplane = n0 / NHID;
    const int obase  = (n0 % NHID) + wc;
    unsigned short* Cp = C + (size_t)kplane * MDIM * NHID;
    #pragma unroll
    for (int m = 0; m < 4; ++m) {
        int row = m0 + wr + m * 16 + kq * 4;
        #pragma unroll
        for (int n = 0; n < 4; ++n) {
            int col = obase + n * 16 + lr;
            #pragma unroll
            for (int j = 0; j < 4; ++j) {
                Cp[(size_t)(row + j) * NHID + col] = f2bf(acc[m][n][j]);
            }
        }
    }
}

// ---------------- epilogue: activations + mix, write y_pred & new_hidden (f32) ----------------
__global__ void epilogue(const unsigned short* __restrict__ C,
                         const float* __restrict__ bg, const float* __restrict__ bh,
                         const float* __restrict__ bfg, const float* __restrict__ bfh,
                         const float* __restrict__ bp,
                         float* __restrict__ out) {
    int idx = blockIdx.x * 256 + threadIdx.x;   // 8 elems / thread
    size_t e = (size_t)idx * 8;
    int o = (int)(e & (NHID - 1));
    const size_t PL = (size_t)MDIM * NHID;

    ushort8v vg  = *(const ushort8v*)(C + 0 * PL + e);
    ushort8v vh  = *(const ushort8v*)(C + 1 * PL + e);
    ushort8v vfg = *(const ushort8v*)(C + 2 * PL + e);
    ushort8v vfh = *(const ushort8v*)(C + 3 * PL + e);
    ushort8v vp  = *(const ushort8v*)(C + 4 * PL + e);

    float bgv[8], bhv[8], bfgv[8], bfhv[8], bpv[8];
    *(float4*)bgv  = *(const float4*)(bg + o);  *(float4*)(bgv + 4)  = *(const float4*)(bg + o + 4);
    *(float4*)bhv  = *(const float4*)(bh + o);  *(float4*)(bhv + 4)  = *(const float4*)(bh + o + 4);
    *(float4*)bfgv = *(const float4*)(bfg + o); *(float4*)(bfgv + 4) = *(const float4*)(bfg + o + 4);
    *(float4*)bfhv = *(const float4*)(bfh + o); *(float4*)(bfhv + 4) = *(const float4*)(bfh + o + 4);
    *(float4*)bpv  = *(const float4*)(bp + o);  *(float4*)(bpv + 4)  = *(const float4*)(bp + o + 4);

    float yv[8], nhv[8];
    #pragma unroll
    for (int j = 0; j < 8; ++j) {
        float g    = tanhf(bf2f(vg[j]) + bgv[j]);
        float hh   = tanhf(bf2f(vh[j]) + bhv[j]);
        float s    = bf2f(vfg[j]) + bfgv[j] + bf2f(vfh[j]) + bfhv[j];
        float gate = 1.0f / (1.0f + __expf(-s));
        float nh   = g * (1.0f - gate) + gate * hh;
        nhv[j] = nh;
        yv[j]  = bf2f(vp[j]) + bpv[j] + nh;
    }
    *(float4*)(out + e)          = *(float4*)yv;
    *(float4*)(out + e + 4)      = *(float4*)(yv + 4);
    *(float4*)(out + PL + e)     = *(float4*)nhv;
    *(float4*)(out + PL + e + 4) = *(float4*)(nhv + 4);
}

extern "C" void kernel_launch(void* const* d_in, const int* in_sizes, int n_in,
                              void* d_out, int out_size, void* d_ws, size_t ws_size,
                              hipStream_t stream) {
    const float* x      = (const float*)d_in[0];
    const float* hidden = (const float*)d_in[1];
    const float* mask   = (const float*)d_in[2];
    const float* Wg     = (const float*)d_in[3];
    const float* bg     = (const float*)d_in[4];
    const float* Wh     = (const float*)d_in[5];
    const float* bh     = (const float*)d_in[6];
    const float* Wfg    = (const float*)d_in[7];
    const float* bfg    = (const float*)d_in[8];
    const float* Wfh    = (const float*)d_in[9];
    const float* bfh    = (const float*)d_in[10];
    const float* Wp     = (const float*)d_in[11];
    const float* bp     = (const float*)d_in[12];
    float* out = (float*)d_out;

    // workspace layout (bytes): xc 10,485,760 | Wm 52,428,800 | C 41,943,040 = 100 MB
    const size_t need = (size_t)MDIM * KDIM * 2 + (size_t)5 * NHID * KDIM * 2
                      + (size_t)5 * MDIM * NHID * 2;
    if (ws_size < need) return;   // signals cleanly as wrong-output if ws too small

    unsigned short* xc = (unsigned short*)d_ws;
    unsigned short* Wm = xc + (size_t)MDIM * KDIM;
    unsigned short* C  = Wm + (size_t)5 * NHID * KDIM;

    prep_xc<<<MDIM * KDIM / 8 / 256, 256, 0, stream>>>(x, hidden, xc);
    prep_wm<<<NHID * KDIM / 4 / 256, 256, 0, stream>>>(Wg, Wh, Wfg, Wfh, Wp, mask, Wm);
    dim3 grid(5 * NHID / BN, MDIM / BM);
    gemm_bt<<<grid, 256, 0, stream>>>(xc, Wm, C);
    epilogue<<<MDIM * NHID / 8 / 256, 256, 0, stream>>>(C, bg, bh, bfg, bfh, bp, out);
}

// Round 2
// 154.351 us; speedup vs baseline: 1.2166x; 1.2166x over previous
//
#include <hip/hip_runtime.h>

#define MDIM 2048   // B
#define KD   2560   // HEAD
#define NHID 2048   // N_HID
#define INF  512
#define NTOT 10240  // 5*NHID
#define NS   40     // K-steps of 64

typedef __attribute__((ext_vector_type(4))) float f32x4;
typedef __attribute__((ext_vector_type(8))) short short8;
typedef __attribute__((ext_vector_type(8))) unsigned short ushort8v;
typedef __attribute__((ext_vector_type(4))) unsigned short ushort4v;

#define AS1 __attribute__((address_space(1)))
#define AS3 __attribute__((address_space(3)))

__device__ __forceinline__ unsigned short f2bf(float f) {
    unsigned u = __float_as_uint(f);
    u += 0x7fffu + ((u >> 16) & 1u);
    return (unsigned short)(u >> 16);
}
__device__ __forceinline__ float bf2f(unsigned short s) {
    return __uint_as_float(((unsigned)s) << 16);
}

// ---------------- prep: xc = concat(x, hidden) -> bf16 [MDIM][KD] ----------------
__global__ void prep_xc(const float* __restrict__ x, const float* __restrict__ h,
                        unsigned short* __restrict__ xc) {
    int idx = blockIdx.x * 256 + threadIdx.x;
    int e = idx * 8;
    int b = e / KD;
    int c = e - b * KD;
    const float* src = (c < INF) ? (x + (size_t)b * INF + c)
                                 : (h + (size_t)b * NHID + (c - INF));
    float4 v0 = *(const float4*)src;
    float4 v1 = *(const float4*)(src + 4);
    ushort8v o;
    o[0] = f2bf(v0.x); o[1] = f2bf(v0.y); o[2] = f2bf(v0.z); o[3] = f2bf(v0.w);
    o[4] = f2bf(v1.x); o[5] = f2bf(v1.y); o[6] = f2bf(v1.z); o[7] = f2bf(v1.w);
    *(ushort8v*)(xc + e) = o;
}

// ---------------- prep: Wm[k] = W_k * mask -> bf16, 5 planes = [NTOT][KD] ----------------
__global__ void prep_wm(const float* __restrict__ Wg, const float* __restrict__ Wh,
                        const float* __restrict__ Wfg, const float* __restrict__ Wfh,
                        const float* __restrict__ Wp, const float* __restrict__ mask,
                        unsigned short* __restrict__ Wm) {
    int idx = blockIdx.x * 256 + threadIdx.x;
    size_t e = (size_t)idx * 4;
    const size_t PL = (size_t)NHID * KD;
    float4 m = *(const float4*)(mask + e);
    const float* Ws[5] = {Wg, Wh, Wfg, Wfh, Wp};
    #pragma unroll
    for (int k = 0; k < 5; ++k) {
        float4 w = *(const float4*)(Ws[k] + e);
        ushort4v o;
        o[0] = f2bf(w.x * m.x); o[1] = f2bf(w.y * m.y);
        o[2] = f2bf(w.z * m.z); o[3] = f2bf(w.w * m.w);
        *(ushort4v*)(Wm + k * PL + e) = o;
    }
}

// ---------------- 8-phase GEMM: C[2048][10240] = A (2048xK) . B^T (10240xK) ----------------
// BM=256 BN=320 BK=64, 8 waves (2M x 4N), per-wave 128x80, grid 32x8 = 256 blocks.
// LDS double-buffered, XOR swizzle slot^=(row&7) via pre-swizzled global source.
// Counted vmcnt(9) at end of P0 and P3; never drained to 0 in the loop.
#define MFMA(d, va, vb) d = __builtin_amdgcn_mfma_f32_16x16x32_bf16(va, vb, d, 0, 0, 0)

__global__ __launch_bounds__(512, 2) void gemm8p(
    const unsigned short* __restrict__ A,
    const unsigned short* __restrict__ B,
    unsigned short* __restrict__ C) {
    __shared__ unsigned short lsA[2][256 * 64];   // 64 KB
    __shared__ unsigned short lsB[2][320 * 64];   // 80 KB

    const int tid  = threadIdx.x;
    const int lane = tid & 63;
    const int w    = tid >> 6;       // 0..7
    const int wm   = w >> 2;         // 0..1
    const int wn   = w & 3;          // 0..3
    const int lr   = lane & 15;
    const int kq   = lane >> 4;      // 0..3
    const int l7   = lane & 7;
    const int m0   = blockIdx.y * 256;
    const int n0   = blockIdx.x * 320;

    const unsigned short* gA = A + (size_t)m0 * KD;
    const unsigned short* gB = B + (size_t)n0 * KD;
    // per-lane source offset: 8 rows x 8 16B-slots, slot pre-swizzled by row&7
    const int soff = (lane >> 3) * KD + (((lane & 7) ^ (lane >> 3)) << 3);

    const int ar0 = (w >> 2) * 128 + (w & 3) * 8;  // + 32*j  -> A rows [32j..) two halves
    const int br0 = (w >> 1) * 80 + (w & 1) * 8;   // + 16j (j<2) / 32+16(j-2)

#define SA(j, t, b) __builtin_amdgcn_global_load_lds( \
        (const AS1 unsigned int*)(gA + (size_t)(ar0 + 32 * (j)) * KD + (t) * 64 + soff), \
        (AS3 unsigned int*)(&lsA[b][(ar0 + 32 * (j)) * 64]), 16, 0, 0)
#define SB(j, t, b) __builtin_amdgcn_global_load_lds( \
        (const AS1 unsigned int*)(gB + (size_t)(br0 + ((j) < 2 ? 16 * (j) : 32 + 16 * ((j) - 2))) * KD + (t) * 64 + soff), \
        (AS3 unsigned int*)(&lsB[b][(br0 + ((j) < 2 ? 16 * (j) : 32 + 16 * ((j) - 2))) * 64]), 16, 0, 0)

    // swizzled ds_read col offsets (ushorts) for ksub 0/1
    const int c0 = ((0 + kq) ^ l7) << 3;
    const int c1 = ((4 + kq) ^ l7) << 3;
    const int arow = wm * 128 + lr;   // + 16*m
    const int brow = wn * 80 + lr;    // + 16*n

#define LDA(dst, b, m, cs) dst = *(const short8*)&lsA[b][(arow + 16 * (m)) * 64 + (cs)]
#define LDB(dst, b, n, cs) dst = *(const short8*)&lsB[b][(brow + 16 * (n)) * 64 + (cs)]

#define FBAR() do { asm volatile("" ::: "memory"); __builtin_amdgcn_s_barrier(); asm volatile("" ::: "memory"); } while (0)
#define VBAR() do { asm volatile("s_waitcnt vmcnt(9)" ::: "memory"); __builtin_amdgcn_s_barrier(); asm volatile("" ::: "memory"); } while (0)

    f32x4 acc[8][5] = {};

    // prologue: step0 full (P0-needs first), step1's Ah0+Bp0
    SA(0, 0, 0); SA(1, 0, 0); SB(0, 0, 0); SB(1, 0, 0);
    SA(2, 0, 0); SA(3, 0, 0); SB(2, 0, 0); SB(3, 0, 0); SB(4, 0, 0);
    SA(0, 1, 1); SA(1, 1, 1); SB(0, 1, 1); SB(1, 1, 1);
    VBAR();

    for (int kt = 0; kt < NS; ++kt) {
        const int bc = kt & 1, bo = bc ^ 1;
        short8 fa[4][2], fb[2][2], fc[3][2];

        // ---- P0: Mreps 0-3 x Nreps 0-1 ----
        #pragma unroll
        for (int m = 0; m < 4; ++m) { LDA(fa[m][0], bc, m, c0); LDA(fa[m][1], bc, m, c1); }
        #pragma unroll
        for (int n = 0; n < 2; ++n) { LDB(fb[n][0], bc, n, c0); LDB(fb[n][1], bc, n, c1); }
        if (kt < NS - 1) { SA(2, kt + 1, bo); SA(3, kt + 1, bo); SB(2, kt + 1, bo); SB(3, kt + 1, bo); SB(4, kt + 1, bo); }
        FBAR();
        __builtin_amdgcn_s_setprio(1);
        #pragma unroll
        for (int m = 0; m < 4; ++m)
            #pragma unroll
            for (int n = 0; n < 2; ++n) { MFMA(acc[m][n], fa[m][0], fb[n][0]); MFMA(acc[m][n], fa[m][1], fb[n][1]); }
        __builtin_amdgcn_s_setprio(0);
        VBAR();

        // ---- P1: Mreps 0-3 x Nreps 2-4 ----
        #pragma unroll
        for (int j = 0; j < 3; ++j) { LDB(fc[j][0], bc, 2 + j, c0); LDB(fc[j][1], bc, 2 + j, c1); }
        FBAR();
        __builtin_amdgcn_s_setprio(1);
        #pragma unroll
        for (int m = 0; m < 4; ++m)
            #pragma unroll
            for (int j = 0; j < 3; ++j) { MFMA(acc[m][2 + j], fa[m][0], fc[j][0]); MFMA(acc[m][2 + j], fa[m][1], fc[j][1]); }
        __builtin_amdgcn_s_setprio(0);
        FBAR();

        // ---- P2: Mreps 4-7 x Nreps 0-1 ----
        #pragma unroll
        for (int m = 0; m < 4; ++m) { LDA(fa[m][0], bc, 4 + m, c0); LDA(fa[m][1], bc, 4 + m, c1); }
        #pragma unroll
        for (int n = 0; n < 2; ++n) { LDB(fb[n][0], bc, n, c0); LDB(fb[n][1], bc, n, c1); }
        if (kt < NS - 2) { SA(0, kt + 2, bc); SA(1, kt + 2, bc); }
        FBAR();
        __builtin_amdgcn_s_setprio(1);
        #pragma unroll
        for (int m = 0; m < 4; ++m)
            #pragma unroll
            for (int n = 0; n < 2; ++n) { MFMA(acc[4 + m][n], fa[m][0], fb[n][0]); MFMA(acc[4 + m][n], fa[m][1], fb[n][1]); }
        __builtin_amdgcn_s_setprio(0);
        FBAR();

        // ---- P3: Mreps 4-7 x Nreps 2-4 ----
        #pragma unroll
        for (int j = 0; j < 3; ++j) { LDB(fc[j][0], bc, 2 + j, c0); LDB(fc[j][1], bc, 2 + j, c1); }
        if (kt < NS - 2) { SB(0, kt + 2, bc); SB(1, kt + 2, bc); }
        FBAR();
        __builtin_amdgcn_s_setprio(1);
        #pragma unroll
        for (int m = 0; m < 4; ++m)
            #pragma unroll
            for (int j = 0; j < 3; ++j) { MFMA(acc[4 + m][2 + j], fa[m][0], fc[j][0]); MFMA(acc[4 + m][2 + j], fa[m][1], fc[j][1]); }
        __builtin_amdgcn_s_setprio(0);
        VBAR();
    }

    // C write: row = m0 + wm*128 + m*16 + kq*4 + j ; col = n0 + wn*80 + n*16 + lr
    #pragma unroll
    for (int m = 0; m < 8; ++m) {
        int row = m0 + wm * 128 + m * 16 + kq * 4;
        #pragma unroll
        for (int n = 0; n < 5; ++n) {
            int col = n0 + wn * 80 + n * 16 + lr;
            #pragma unroll
            for (int j = 0; j < 4; ++j)
                C[(size_t)(row + j) * NTOT + col] = f2bf(acc[m][n][j]);
        }
    }
#undef SA
#undef SB
#undef LDA
#undef LDB
#undef FBAR
#undef VBAR
}

// ---------------- epilogue: activations + mix -> y_pred, new_hidden (f32) ----------------
// C layout now [MDIM][NTOT]; plane k at col offset k*NHID.
__global__ void epilogue(const unsigned short* __restrict__ C,
                         const float* __restrict__ bg, const float* __restrict__ bh,
                         const float* __restrict__ bfg, const float* __restrict__ bfh,
                         const float* __restrict__ bp,
                         float* __restrict__ out) {
    int idx = blockIdx.x * 256 + threadIdx.x;
    size_t e = (size_t)idx * 8;
    int b = (int)(e >> 11);          // e / NHID
    int o = (int)(e & (NHID - 1));
    const size_t PL = (size_t)MDIM * NHID;
    const unsigned short* row = C + (size_t)b * NTOT + o;

    ushort8v vg  = *(const ushort8v*)(row + 0 * NHID);
    ushort8v vh  = *(const ushort8v*)(row + 1 * NHID);
    ushort8v vfg = *(const ushort8v*)(row + 2 * NHID);
    ushort8v vfh = *(const ushort8v*)(row + 3 * NHID);
    ushort8v vp  = *(const ushort8v*)(row + 4 * NHID);

    float bgv[8], bhv[8], bfgv[8], bfhv[8], bpv[8];
    *(float4*)bgv  = *(const float4*)(bg + o);  *(float4*)(bgv + 4)  = *(const float4*)(bg + o + 4);
    *(float4*)bhv  = *(const float4*)(bh + o);  *(float4*)(bhv + 4)  = *(const float4*)(bh + o + 4);
    *(float4*)bfgv = *(const float4*)(bfg + o); *(float4*)(bfgv + 4) = *(const float4*)(bfg + o + 4);
    *(float4*)bfhv = *(const float4*)(bfh + o); *(float4*)(bfhv + 4) = *(const float4*)(bfh + o + 4);
    *(float4*)bpv  = *(const float4*)(bp + o);  *(float4*)(bpv + 4)  = *(const float4*)(bp + o + 4);

    float yv[8], nhv[8];
    #pragma unroll
    for (int j = 0; j < 8; ++j) {
        float g    = tanhf(bf2f(vg[j]) + bgv[j]);
        float hh   = tanhf(bf2f(vh[j]) + bhv[j]);
        float s    = bf2f(vfg[j]) + bfgv[j] + bf2f(vfh[j]) + bfhv[j];
        float gate = 1.0f / (1.0f + __expf(-s));
        float nh   = g * (1.0f - gate) + gate * hh;
        nhv[j] = nh;
        yv[j]  = bf2f(vp[j]) + bpv[j] + nh;
    }
    *(float4*)(out + e)          = *(float4*)yv;
    *(float4*)(out + e + 4)      = *(float4*)(yv + 4);
    *(float4*)(out + PL + e)     = *(float4*)nhv;
    *(float4*)(out + PL + e + 4) = *(float4*)(nhv + 4);
}

extern "C" void kernel_launch(void* const* d_in, const int* in_sizes, int n_in,
                              void* d_out, int out_size, void* d_ws, size_t ws_size,
                              hipStream_t stream) {
    const float* x      = (const float*)d_in[0];
    const float* hidden = (const float*)d_in[1];
    const float* mask   = (const float*)d_in[2];
    const float* Wg     = (const float*)d_in[3];
    const float* bg     = (const float*)d_in[4];
    const float* Wh     = (const float*)d_in[5];
    const float* bh     = (const float*)d_in[6];
    const float* Wfg    = (const float*)d_in[7];
    const float* bfg    = (const float*)d_in[8];
    const float* Wfh    = (const float*)d_in[9];
    const float* bfh    = (const float*)d_in[10];
    const float* Wp     = (const float*)d_in[11];
    const float* bp     = (const float*)d_in[12];
    float* out = (float*)d_out;

    const size_t need = (size_t)MDIM * KD * 2 + (size_t)NTOT * KD * 2
                      + (size_t)MDIM * NTOT * 2;
    if (ws_size < need) return;

    unsigned short* xc = (unsigned short*)d_ws;
    unsigned short* Wm = xc + (size_t)MDIM * KD;
    unsigned short* C  = Wm + (size_t)NTOT * KD;

    prep_xc<<<MDIM * KD / 8 / 256, 256, 0, stream>>>(x, hidden, xc);
    prep_wm<<<NHID * KD / 4 / 256, 256, 0, stream>>>(Wg, Wh, Wfg, Wfh, Wp, mask, Wm);
    dim3 grid(NTOT / 320, MDIM / 256);
    gemm8p<<<grid, 512, 0, stream>>>(xc, Wm, C);
    epilogue<<<MDIM * NHID / 8 / 256, 256, 0, stream>>>(C, bg, bh, bfg, bfh, bp, out);
}